// Round 9
// baseline (133.788 us; speedup 1.0000x reference)
//
#include <hip/hip_runtime.h>
#include <math.h>

#define BDIM 512
#define IDIM 256
#define ODIM 512

// 16B table entry: correctly-rounded fp64 reciprocal of den + the comp value.
struct __align__(16) XT { double r; float c; float pad; };

// jnp.minimum(q, 1.0): NaN-propagating min with 1.0
__device__ __forceinline__ float np_min1(float q) {
    float m = fminf(q, 1.0f);
    return (q != q) ? q : m;
}

// np.argmin update: strict < (first occurrence wins), NaN-first & sticky.
__device__ __forceinline__ bool np_argmin_better(float s, float best) {
    return (s < best) || (isnan(s) && !isnan(best));
}

// Correctly-rounded fp32 divide num/den as RN32(num * r), r = RN64(1/den).
// (no fp32/fp32 quotient is a 25-bit midpoint -> exclusion >= 2^-49 >> 2^-51.9
// rel err; den==0 -> r=+INF -> IEEE num/0.) Bit-stable since R2 (absmax pinned).
__device__ __forceinline__ float q32(float num, double r) {
    return (float)((double)num * r);
}

// async global->LDS, 16B/lane; global src is PER-LANE, LDS dest = base+lane*16.
typedef const __attribute__((address_space(1))) unsigned int* gu32p;
typedef __attribute__((address_space(3))) unsigned int* lu32p;
__device__ __forceinline__ void async_cp16(const float* g, float* l) {
    __builtin_amdgcn_global_load_lds((gu32p)(const void*)g, (lu32p)(void*)l, 16, 0, 0);
}

// K1: rel_x[i, o-half] = 1 - S/D, sequential-in-b (numpy order).
// Grid 512 = (i, oh), 256 thr. BARRIER-FREE per-wave t streaming: wave wv
// stages only its own 64-col window (per-lane global addrs: lane l covers
// row l>>4, cols (l&15)*4..+3 -> LDS [4 rows][64 cols] == lane*16 layout).
// Triple-buffered, own-wave counted vmcnt, one barrier total (xtab).
#define XCH 8
#define XNC (BDIM / XCH)   // 64
__global__ __launch_bounds__(256) void relx_kernel(const float* __restrict__ x,
                                                   const float* __restrict__ t,
                                                   float* __restrict__ relx) {
    __shared__ float tbuf[4][3][XCH * 64];   // 24 KB (per-wave private slices)
    __shared__ XT    xtab[BDIM];             // 8 KB -> 32 KB total
    const int tid = threadIdx.x;             // 0..255
    const int i   = blockIdx.x >> 1;         // 0..255
    const int obase = (blockIdx.x & 1) * 256;
    const int l = tid & 63, wv = tid >> 6;   // 4 waves
    const int colbase = obase + wv * 64;     // wave's column window

    // build x-table: one fp64 divide per (b,i), 2 per thread, no chains
    for (int b = tid; b < BDIM; b += 256) {
        float xv  = x[(size_t)b * IDIM + i]; // strided gather, once
        float xc  = __fsub_rn(1.0f, xv);     // x_comp
        float den = __fsub_rn(1.0f, xc);     // NOT simply xv (rounding!)
        XT e; e.r = 1.0 / (double)den; e.c = xc; e.pad = 0.0f;
        xtab[b] = e;                         // den==0 -> r=+INF (IEEE)
    }
    asm volatile("s_waitcnt vmcnt(0)" ::: "memory");  // clean slate for counting
    #pragma unroll
    for (int c0 = 0; c0 < 2; ++c0) {         // issue chunks 0,1: 2 ops each
        #pragma unroll
        for (int rr = 0; rr < 2; ++rr) {
            size_t row = (size_t)(c0 * XCH + rr * 4 + (l >> 4));
            const float* g = t + row * ODIM + colbase + (l & 15) * 4;
            async_cp16(g, &tbuf[wv][c0][rr * 256 + l * 4]);
        }
    }
    asm volatile("s_waitcnt lgkmcnt(0)" ::: "memory");  // xtab ds_writes done
    __builtin_amdgcn_s_barrier();                       // xtab visible (only barrier)

    float S = 0.0f, D = 0.0f;
    for (int c = 0; c < XNC; ++c) {
        // outstanding: chunk c (2) + chunk c+1 (2) -> keep next chunk in flight
        if (c == XNC - 1) asm volatile("s_waitcnt vmcnt(0)" ::: "memory");
        else              asm volatile("s_waitcnt vmcnt(2)" ::: "memory");
        const float* tb = &tbuf[wv][c % 3][0];
        #pragma unroll
        for (int u = 0; u < XCH; ++u) {
            float tv = tb[u * 64 + l];       // 2-way bank (free)
            XT e = xtab[c * XCH + u];        // uniform broadcast b128
            float tc  = __fsub_rn(1.0f, tv); // t_comp
            float num = __fsub_rn(tc, e.c);
            float q   = np_min1(q32(num, e.r));
            S = __fadd_rn(S, q);             // exact sequential order
            D = __fadd_rn(D, e.c);
        }
        asm volatile("" ::: "memory");
        if (c + 2 < XNC) {                   // prefetch c+2 over own slot (c-1)%3
            int sl = (c + 2) % 3;
            #pragma unroll
            for (int rr = 0; rr < 2; ++rr) {
                size_t row = (size_t)((c + 2) * XCH + rr * 4 + (l >> 4));
                const float* g = t + row * ODIM + colbase + (l & 15) * 4;
                async_cp16(g, &tbuf[wv][sl][rr * 256 + l * 4]);
            }
        }
    }
    relx[(size_t)i * ODIM + obase + tid] = __fsub_rn(1.0f, __fdiv_rn(S, D));
}

// K2: rel_w[b,o] = 1 - S/D, sequential-in-i. Block = o (512 thr = b).
// w-table in LDS; output TRANSPOSED so the store coalesces. (R7, proven.)
__global__ __launch_bounds__(512) void relw_kernel(const float* __restrict__ w,
                                                   const float* __restrict__ t,
                                                   float* __restrict__ relwT) {
    __shared__ XT wtab[IDIM];                // 4 KB
    const int b = threadIdx.x;               // 0..511
    const int o = blockIdx.x;                // 0..511
    if (b < IDIM) {
        float wvv = w[(size_t)b * ODIM + o]; // strided gather, once
        float wc  = __fsub_rn(1.0f, wvv);    // w_comp
        float den = __fsub_rn(1.0f, wc);
        XT e; e.r = 1.0 / (double)den; e.c = wc; e.pad = 0.0f;
        wtab[b] = e;
    }
    float tc = __fsub_rn(1.0f, t[(size_t)b * ODIM + o]);  // strided, once
    __syncthreads();
    float S = 0.0f, D = 0.0f;
    #pragma unroll 8
    for (int i = 0; i < IDIM; ++i) {
        XT e = wtab[i];                      // uniform broadcast b128
        float num = __fsub_rn(tc, e.c);
        float q   = np_min1(q32(num, e.r));
        S = __fadd_rn(S, q);                 // exact sequential order
        D = __fadd_rn(D, e.c);
    }
    relwT[(size_t)o * BDIM + b] = __fsub_rn(1.0f, __fdiv_rn(S, D));  // coalesced
}

// K3: both argmins + gathers (scans MERGED back per thread - R8 split hurt).
// Grid 1024 = (b, oh), 256 thr. BARRIER-FREE per-wave (w, relx) streaming,
// triple-buffered, own-wave counted vmcnt; one barrier total (xrow).
#define OCH 8
#define ONC (IDIM / OCH)   // 32
__global__ __launch_bounds__(256) void out_kernel(const float* __restrict__ x,
                                                  const float* __restrict__ w,
                                                  const float* __restrict__ relx,
                                                  const float* __restrict__ relwT,
                                                  float* __restrict__ out) {
    __shared__ float wbuf[4][3][OCH * 64];   // 24 KB (per-wave private)
    __shared__ float rbuf[4][3][OCH * 64];   // 24 KB
    __shared__ float xrow[IDIM];             // 1 KB -> 49 KB, 3 blocks/CU
    const int tid = threadIdx.x;             // 0..255
    const int b   = blockIdx.x >> 1;         // 0..511
    const int obase = (blockIdx.x & 1) * 256;
    const int l = tid & 63, wv = tid >> 6;   // 4 waves
    const int colbase = obase + wv * 64;
    const int o = obase + tid;

    xrow[tid] = x[(size_t)b * IDIM + tid];   // coalesced (256 == IDIM)
    float rw = relwT[(size_t)o * BDIM + b];  // gather, 1/thread
    asm volatile("s_waitcnt vmcnt(0)" ::: "memory");  // clean count
    #pragma unroll
    for (int c0 = 0; c0 < 2; ++c0) {         // issue chunks 0,1: 4 ops each
        #pragma unroll
        for (int rr = 0; rr < 2; ++rr) {
            size_t row = (size_t)(c0 * OCH + rr * 4 + (l >> 4));
            const float* gw = w    + row * ODIM + colbase + (l & 15) * 4;
            const float* gr = relx + row * ODIM + colbase + (l & 15) * 4;
            async_cp16(gw, &wbuf[wv][c0][rr * 256 + l * 4]);
            async_cp16(gr, &rbuf[wv][c0][rr * 256 + l * 4]);
        }
    }
    asm volatile("s_waitcnt lgkmcnt(0)" ::: "memory");  // xrow ds_write done
    __builtin_amdgcn_s_barrier();                       // xrow visible (only barrier)

    float bw = (float)INFINITY, bx = (float)INFINITY;  // +INF seed == first-occ
    int iw = 0, ix = 0;
    for (int c = 0; c < ONC; ++c) {
        // outstanding: chunk c (4) + chunk c+1 (4) -> keep 4 in flight
        if (c == ONC - 1) asm volatile("s_waitcnt vmcnt(0)" ::: "memory");
        else              asm volatile("s_waitcnt vmcnt(4)" ::: "memory");
        const float* wb = &wbuf[wv][c % 3][0];
        const float* rb = &rbuf[wv][c % 3][0];
        #pragma unroll
        for (int u = 0; u < OCH; ++u) {
            int ii = c * OCH + u;
            float a  = wb[u * 64 + l];       // 2-way bank (free)
            float rl = rb[u * 64 + l];
            float xv = xrow[ii];             // uniform broadcast
            float sw = __fsub_rn(__fadd_rn(a,  rw), __fmul_rn(a,  rw));
            float sx = __fsub_rn(__fadd_rn(xv, rl), __fmul_rn(xv, rl));
            if (np_argmin_better(sw, bw)) { bw = sw; iw = ii; }  // sequential
            if (np_argmin_better(sx, bx)) { bx = sx; ix = ii; }
        }
        asm volatile("" ::: "memory");
        if (c + 2 < ONC) {                   // prefetch c+2 over own slot (c-1)%3
            int sl = (c + 2) % 3;
            #pragma unroll
            for (int rr = 0; rr < 2; ++rr) {
                size_t row = (size_t)((c + 2) * OCH + rr * 4 + (l >> 4));
                const float* gw = w    + row * ODIM + colbase + (l & 15) * 4;
                const float* gr = relx + row * ODIM + colbase + (l & 15) * 4;
                async_cp16(gw, &wbuf[wv][sl][rr * 256 + l * 4]);
                async_cp16(gr, &rbuf[wv][sl][rr * 256 + l * 4]);
            }
        }
    }
    // epilogue: gather + max + store (xrow stable since prologue)
    float cw = fmaxf(xrow[iw], w[(size_t)iw * ODIM + o]);
    float cx = fmaxf(xrow[ix], w[(size_t)ix * ODIM + o]);
    out[(size_t)BDIM * ODIM + (size_t)b * ODIM + o] = cw;  // chosen_w = out 1
    out[(size_t)b * ODIM + o] = cx;                        // chosen_x = out 0
}

extern "C" void kernel_launch(void* const* d_in, const int* in_sizes, int n_in,
                              void* d_out, int out_size, void* d_ws, size_t ws_size,
                              hipStream_t stream) {
    const float* x = (const float*)d_in[0];  // (B, I)
    const float* w = (const float*)d_in[1];  // (I, O)
    const float* t = (const float*)d_in[2];  // (B, O)
    float* out = (float*)d_out;              // [chosen_x | chosen_w]

    char* ws = (char*)d_ws;
    float* relx  = (float*)(ws);                         // I*O*4 = 512 KB
    float* relwT = (float*)(ws + (IDIM * ODIM * 4));     // O*B*4 = 1 MB

    hipLaunchKernelGGL(relx_kernel, dim3(2 * IDIM), dim3(256), 0, stream, x, t, relx);
    hipLaunchKernelGGL(relw_kernel, dim3(ODIM),     dim3(512), 0, stream, w, t, relwT);
    hipLaunchKernelGGL(out_kernel,  dim3(2 * BDIM), dim3(256), 0, stream, x, w, relx, relwT, out);
}

// Round 10
// 106.222 us; speedup vs baseline: 1.2595x; 1.2595x over previous
//
#include <hip/hip_runtime.h>
#include <math.h>

#define BDIM 512
#define IDIM 256
#define ODIM 512

// 16B table entry: correctly-rounded fp64 reciprocal of den, comp, raw value.
struct __align__(16) XT { double r; float c; float pad; };

// jnp.minimum(q, 1.0): NaN-propagating min with 1.0
__device__ __forceinline__ float np_min1(float q) {
    float m = fminf(q, 1.0f);
    return (q != q) ? q : m;
}

// np.argmin update: strict < (first occurrence wins), NaN-first & sticky.
__device__ __forceinline__ bool np_argmin_better(float s, float best) {
    return (s < best) || (isnan(s) && !isnan(best));
}

// Correctly-rounded fp32 divide num/den as RN32(num * r), r = RN64(1/den).
// (no fp32/fp32 quotient is a 25-bit midpoint -> exclusion >= 2^-49 >> 2^-51.9
// rel err; den==0 -> r=+INF -> IEEE num/0.) Bit-stable since R2 (absmax pinned).
__device__ __forceinline__ float q32(float num, double r) {
    return (float)((double)num * r);
}

// async global->LDS, 16B/lane; global src is PER-LANE, LDS dest = base+lane*16.
typedef const __attribute__((address_space(1))) unsigned int* gu32p;
typedef __attribute__((address_space(3))) unsigned int* lu32p;
__device__ __forceinline__ void async_cp16(const float* g, float* l) {
    __builtin_amdgcn_global_load_lds((gu32p)(const void*)g, (lu32p)(void*)l, 16, 0, 0);
}

// K1: rel_x[i, o-half] = 1 - S/D, sequential-in-b (numpy order).
// Grid 512 = (i, oh), 256 thr. Barrier-free per-wave t streaming (R9).
#define XCH 8
#define XNC (BDIM / XCH)   // 64
__global__ __launch_bounds__(256) void relx_kernel(const float* __restrict__ x,
                                                   const float* __restrict__ t,
                                                   float* __restrict__ relx) {
    __shared__ float tbuf[4][3][XCH * 64];   // 24 KB (per-wave private slices)
    __shared__ XT    xtab[BDIM];             // 8 KB -> 32 KB total
    const int tid = threadIdx.x;             // 0..255
    const int i   = blockIdx.x >> 1;         // 0..255
    const int obase = (blockIdx.x & 1) * 256;
    const int l = tid & 63, wv = tid >> 6;   // 4 waves
    const int colbase = obase + wv * 64;     // wave's column window

    // build x-table: one fp64 divide per (b,i), 2 per thread, no chains
    for (int b = tid; b < BDIM; b += 256) {
        float xv  = x[(size_t)b * IDIM + i]; // strided gather, once
        float xc  = __fsub_rn(1.0f, xv);     // x_comp
        float den = __fsub_rn(1.0f, xc);     // NOT simply xv (rounding!)
        XT e; e.r = 1.0 / (double)den; e.c = xc; e.pad = xv;
        xtab[b] = e;                         // den==0 -> r=+INF (IEEE)
    }
    asm volatile("s_waitcnt vmcnt(0)" ::: "memory");  // clean slate for counting
    #pragma unroll
    for (int c0 = 0; c0 < 2; ++c0) {         // issue chunks 0,1: 2 ops each
        #pragma unroll
        for (int rr = 0; rr < 2; ++rr) {
            size_t row = (size_t)(c0 * XCH + rr * 4 + (l >> 4));
            const float* g = t + row * ODIM + colbase + (l & 15) * 4;
            async_cp16(g, &tbuf[wv][c0][rr * 256 + l * 4]);
        }
    }
    asm volatile("s_waitcnt lgkmcnt(0)" ::: "memory");  // xtab ds_writes done
    __builtin_amdgcn_s_barrier();                       // xtab visible (only barrier)

    float S = 0.0f, D = 0.0f;
    for (int c = 0; c < XNC; ++c) {
        if (c == XNC - 1) asm volatile("s_waitcnt vmcnt(0)" ::: "memory");
        else              asm volatile("s_waitcnt vmcnt(2)" ::: "memory");
        const float* tb = &tbuf[wv][c % 3][0];
        #pragma unroll
        for (int u = 0; u < XCH; ++u) {
            float tv = tb[u * 64 + l];       // 2-way bank (free)
            XT e = xtab[c * XCH + u];        // uniform broadcast b128
            float tc  = __fsub_rn(1.0f, tv); // t_comp
            float num = __fsub_rn(tc, e.c);
            float q   = np_min1(q32(num, e.r));
            S = __fadd_rn(S, q);             // exact sequential order
            D = __fadd_rn(D, e.c);
        }
        asm volatile("" ::: "memory");
        if (c + 2 < XNC) {                   // prefetch c+2 over own slot (c-1)%3
            int sl = (c + 2) % 3;
            #pragma unroll
            for (int rr = 0; rr < 2; ++rr) {
                size_t row = (size_t)((c + 2) * XCH + rr * 4 + (l >> 4));
                const float* g = t + row * ODIM + colbase + (l & 15) * 4;
                async_cp16(g, &tbuf[wv][sl][rr * 256 + l * 4]);
            }
        }
    }
    relx[(size_t)i * ODIM + obase + tid] = __fsub_rn(1.0f, __fdiv_rn(S, D));
}

// K2: FUSED rel_w + ind_w + chosen_w. Block = o (512), thread = b (512).
// wtab holds {1/den, w_comp, raw w}; rw scan then sw argmin scan, both
// pure LDS-broadcast + VALU. chosen_w = max(x[b,iw], w[iw,o]); strided
// store (1/thread). No relwT workspace, no w-streaming in K3.
__global__ __launch_bounds__(512) void relw_out_kernel(const float* __restrict__ x,
                                                       const float* __restrict__ w,
                                                       const float* __restrict__ t,
                                                       float* __restrict__ out) {
    __shared__ XT wtab[IDIM];                // 4 KB
    const int b = threadIdx.x;               // 0..511
    const int o = blockIdx.x;                // 0..511
    if (b < IDIM) {
        float wvv = w[(size_t)b * ODIM + o]; // strided gather, once
        float wc  = __fsub_rn(1.0f, wvv);    // w_comp
        float den = __fsub_rn(1.0f, wc);
        XT e; e.r = 1.0 / (double)den; e.c = wc; e.pad = wvv;
        wtab[b] = e;
    }
    float tc = __fsub_rn(1.0f, t[(size_t)b * ODIM + o]);  // strided, once
    __syncthreads();

    // pass 1: rel_w[b,o], exact sequential order
    float S = 0.0f, D = 0.0f;
    #pragma unroll 8
    for (int i = 0; i < IDIM; ++i) {
        XT e = wtab[i];                      // uniform broadcast b128
        float num = __fsub_rn(tc, e.c);
        float q   = np_min1(q32(num, e.r));
        S = __fadd_rn(S, q);
        D = __fadd_rn(D, e.c);
    }
    float rw = __fsub_rn(1.0f, __fdiv_rn(S, D));

    // pass 2: ind_w = argmin_i fl(fl(w+rw) - fl(w*rw)), sequential scan
    float best = (float)INFINITY; int iw = 0;   // +INF seed == first-occurrence
    #pragma unroll 8
    for (int i = 0; i < IDIM; ++i) {
        float wvv = wtab[i].pad;             // uniform broadcast
        float s = __fsub_rn(__fadd_rn(wvv, rw), __fmul_rn(wvv, rw));
        if (np_argmin_better(s, best)) { best = s; iw = i; }
    }
    float cw = fmaxf(x[(size_t)b * IDIM + iw], wtab[iw].pad);
    out[(size_t)BDIM * ODIM + (size_t)b * ODIM + o] = cw;  // chosen_w = out 1
}

// K3: sx-only argmin + chosen_x. Grid 1024 = (b, oh), 256 thr. Barrier-free
// per-wave relx streaming, triple-buffered; 25 KB LDS -> 4 blocks/CU (grid),
// 16 waves/CU. Coalesced store.
#define OCH 8
#define ONC (IDIM / OCH)   // 32
__global__ __launch_bounds__(256) void outx_kernel(const float* __restrict__ x,
                                                   const float* __restrict__ w,
                                                   const float* __restrict__ relx,
                                                   float* __restrict__ out) {
    __shared__ float rbuf[4][3][OCH * 64];   // 24 KB (per-wave private)
    __shared__ float xrow[IDIM];             // 1 KB -> 25 KB total
    const int tid = threadIdx.x;             // 0..255
    const int b   = blockIdx.x >> 1;         // 0..511
    const int obase = (blockIdx.x & 1) * 256;
    const int l = tid & 63, wv = tid >> 6;   // 4 waves
    const int colbase = obase + wv * 64;
    const int o = obase + tid;

    xrow[tid] = x[(size_t)b * IDIM + tid];   // coalesced (256 == IDIM)
    asm volatile("s_waitcnt vmcnt(0)" ::: "memory");  // clean count
    #pragma unroll
    for (int c0 = 0; c0 < 2; ++c0) {         // issue chunks 0,1: 2 ops each
        #pragma unroll
        for (int rr = 0; rr < 2; ++rr) {
            size_t row = (size_t)(c0 * OCH + rr * 4 + (l >> 4));
            const float* gr = relx + row * ODIM + colbase + (l & 15) * 4;
            async_cp16(gr, &rbuf[wv][c0][rr * 256 + l * 4]);
        }
    }
    asm volatile("s_waitcnt lgkmcnt(0)" ::: "memory");  // xrow ds_write done
    __builtin_amdgcn_s_barrier();                       // xrow visible (only barrier)

    float bx = (float)INFINITY; int ix = 0;  // +INF seed == first-occurrence
    for (int c = 0; c < ONC; ++c) {
        if (c == ONC - 1) asm volatile("s_waitcnt vmcnt(0)" ::: "memory");
        else              asm volatile("s_waitcnt vmcnt(2)" ::: "memory");
        const float* rb = &rbuf[wv][c % 3][0];
        #pragma unroll
        for (int u = 0; u < OCH; ++u) {
            int ii = c * OCH + u;
            float rl = rb[u * 64 + l];       // 2-way bank (free)
            float xv = xrow[ii];             // uniform broadcast
            float s  = __fsub_rn(__fadd_rn(xv, rl), __fmul_rn(xv, rl));
            if (np_argmin_better(s, bx)) { bx = s; ix = ii; }  // sequential
        }
        asm volatile("" ::: "memory");
        if (c + 2 < ONC) {                   // prefetch c+2 over own slot (c-1)%3
            int sl = (c + 2) % 3;
            #pragma unroll
            for (int rr = 0; rr < 2; ++rr) {
                size_t row = (size_t)((c + 2) * OCH + rr * 4 + (l >> 4));
                const float* gr = relx + row * ODIM + colbase + (l & 15) * 4;
                async_cp16(gr, &rbuf[wv][sl][rr * 256 + l * 4]);
            }
        }
    }
    float cx = fmaxf(xrow[ix], w[(size_t)ix * ODIM + o]);  // 1 gather/thread
    out[(size_t)b * ODIM + o] = cx;                        // chosen_x = out 0
}

extern "C" void kernel_launch(void* const* d_in, const int* in_sizes, int n_in,
                              void* d_out, int out_size, void* d_ws, size_t ws_size,
                              hipStream_t stream) {
    const float* x = (const float*)d_in[0];  // (B, I)
    const float* w = (const float*)d_in[1];  // (I, O)
    const float* t = (const float*)d_in[2];  // (B, O)
    float* out = (float*)d_out;              // [chosen_x | chosen_w]

    float* relx = (float*)d_ws;              // I*O*4 = 512 KB

    hipLaunchKernelGGL(relx_kernel,     dim3(2 * IDIM), dim3(256), 0, stream, x, t, relx);
    hipLaunchKernelGGL(relw_out_kernel, dim3(ODIM),     dim3(512), 0, stream, x, w, t, out);
    hipLaunchKernelGGL(outx_kernel,     dim3(2 * BDIM), dim3(256), 0, stream, x, w, relx, out);
}

// Round 11
// 94.831 us; speedup vs baseline: 1.4108x; 1.1201x over previous
//
#include <hip/hip_runtime.h>
#include <math.h>

#define BDIM 512
#define IDIM 256
#define ODIM 512

// 16B table entry: correctly-rounded fp64 reciprocal of den, comp, raw value.
struct __align__(16) XT { double r; float c; float pad; };

// jnp.minimum(q, 1.0): NaN-propagating min with 1.0
__device__ __forceinline__ float np_min1(float q) {
    float m = fminf(q, 1.0f);
    return (q != q) ? q : m;
}

// np.argmin update: strict < (first occurrence wins), NaN-first & sticky.
__device__ __forceinline__ bool np_argmin_better(float s, float best) {
    return (s < best) || (isnan(s) && !isnan(best));
}

// Correctly-rounded fp32 divide num/den as RN32(num * r), r = RN64(1/den).
// (no fp32/fp32 quotient is a 25-bit midpoint -> exclusion >= 2^-49 >> 2^-51.9
// rel err; den==0 -> r=+INF -> IEEE num/0.) Bit-stable since R2 (absmax pinned).
__device__ __forceinline__ float q32(float num, double r) {
    return (float)((double)num * r);
}

// async global->LDS, 16B/lane; global src is PER-LANE, LDS dest = base+lane*16.
typedef const __attribute__((address_space(1))) unsigned int* gu32p;
typedef __attribute__((address_space(3))) unsigned int* lu32p;
__device__ __forceinline__ void async_cp16(const float* g, float* l) {
    __builtin_amdgcn_global_load_lds((gu32p)(const void*)g, (lu32p)(void*)l, 16, 0, 0);
}

// K1 FUSED: blocks 0..255 -> relx role (i = bid, all 512 o, 8 waves each
// owning a 64-col window, barrier-free double-buffered t stream);
// blocks 256..767 -> relw+ind_w+chosen_w role (o = bid-256, thread = b).
// 40 KB LDS union -> 4 blocks/CU; all 768 blocks co-resident -> the two
// independent workloads hide each other's latency.
#define XCH 8
#define XNC (BDIM / XCH)   // 64
__global__ __launch_bounds__(512) void rel_fused_kernel(const float* __restrict__ x,
                                                        const float* __restrict__ w,
                                                        const float* __restrict__ t,
                                                        float* __restrict__ relx,
                                                        float* __restrict__ out) {
    __shared__ __align__(16) char lds[40960];
    const int tid = threadIdx.x;             // 0..511
    const int bid = blockIdx.x;

    if (bid < 256) {
        // ---------------- relx role ----------------
        float (*tbuf)[2][XCH * 64] = (float (*)[2][XCH * 64])lds;  // 8w x 2 x 2KB = 32 KB
        XT* xtab = (XT*)(lds + 32768);                             // 8 KB
        const int i = bid;                   // 0..255
        const int l = tid & 63, wv = tid >> 6;   // 8 waves
        const int colbase = wv * 64;         // wave's 64-col window

        {   // build x-table: one strided gather + one fp64 divide per thread
            float xv  = x[(size_t)tid * IDIM + i];
            float xc  = __fsub_rn(1.0f, xv);     // x_comp
            float den = __fsub_rn(1.0f, xc);     // NOT simply xv (rounding!)
            XT e; e.r = 1.0 / (double)den; e.c = xc; e.pad = xv;
            xtab[tid] = e;                       // den==0 -> r=+INF (IEEE)
        }
        asm volatile("s_waitcnt vmcnt(0)" ::: "memory");  // clean count
        #pragma unroll
        for (int rr = 0; rr < 2; ++rr) {         // issue chunk 0 (2 ops/wave)
            size_t row = (size_t)(rr * 4 + (l >> 4));
            async_cp16(t + row * ODIM + colbase + (l & 15) * 4,
                       &tbuf[wv][0][rr * 256 + l * 4]);
        }
        asm volatile("s_waitcnt lgkmcnt(0)" ::: "memory");  // xtab writes done
        __builtin_amdgcn_s_barrier();                       // xtab visible (only barrier)

        float S = 0.0f, D = 0.0f;
        for (int c = 0; c < XNC; ++c) {
            if (c + 1 < XNC) {               // issue c+1 into the other buffer
                #pragma unroll
                for (int rr = 0; rr < 2; ++rr) {
                    size_t row = (size_t)((c + 1) * XCH + rr * 4 + (l >> 4));
                    async_cp16(t + row * ODIM + colbase + (l & 15) * 4,
                               &tbuf[wv][(c + 1) & 1][rr * 256 + l * 4]);
                }
                asm volatile("s_waitcnt vmcnt(2)" ::: "memory");  // c landed
            } else {
                asm volatile("s_waitcnt vmcnt(0)" ::: "memory");
            }
            const float* tb = &tbuf[wv][c & 1][0];
            #pragma unroll
            for (int u = 0; u < XCH; ++u) {
                float tv = tb[u * 64 + l];       // 2-way bank (free)
                XT e = xtab[c * XCH + u];        // uniform broadcast b128
                float tc  = __fsub_rn(1.0f, tv); // t_comp
                float num = __fsub_rn(tc, e.c);
                float q   = np_min1(q32(num, e.r));
                S = __fadd_rn(S, q);             // exact sequential order
                D = __fadd_rn(D, e.c);
            }
            asm volatile("" ::: "memory");
        }
        relx[(size_t)i * ODIM + tid] = __fsub_rn(1.0f, __fdiv_rn(S, D));
    } else {
        // ---------------- relw + ind_w + chosen_w role ----------------
        XT*    wtab = (XT*)lds;              // 4 KB
        float* wraw = (float*)(lds + 4096);  // 1 KB
        const int b = tid;                   // 0..511
        const int o = bid - 256;             // 0..511
        if (b < IDIM) {
            float wvv = w[(size_t)b * ODIM + o]; // strided gather, once
            float wc  = __fsub_rn(1.0f, wvv);    // w_comp
            float den = __fsub_rn(1.0f, wc);
            XT e; e.r = 1.0 / (double)den; e.c = wc; e.pad = wvv;
            wtab[b] = e;
            wraw[b] = wvv;
        }
        float tc = __fsub_rn(1.0f, t[(size_t)b * ODIM + o]);  // strided, once
        __syncthreads();

        // pass 1: rel_w[b,o], exact sequential order
        float S = 0.0f, D = 0.0f;
        #pragma unroll 8
        for (int i = 0; i < IDIM; ++i) {
            XT e = wtab[i];                  // uniform broadcast b128
            float num = __fsub_rn(tc, e.c);
            float q   = np_min1(q32(num, e.r));
            S = __fadd_rn(S, q);
            D = __fadd_rn(D, e.c);
        }
        float rw = __fsub_rn(1.0f, __fdiv_rn(S, D));

        // pass 2: ind_w = argmin_i fl(fl(w+rw) - fl(w*rw)), sequential scan
        float best = (float)INFINITY; int iw = 0;   // +INF seed == first-occ
        #pragma unroll 16
        for (int i = 0; i < IDIM; ++i) {
            float wvv = wraw[i];             // uniform broadcast b32
            float s = __fsub_rn(__fadd_rn(wvv, rw), __fmul_rn(wvv, rw));
            if (np_argmin_better(s, best)) { best = s; iw = i; }
        }
        float cw = fmaxf(x[(size_t)b * IDIM + iw], wraw[iw]);
        out[(size_t)BDIM * ODIM + (size_t)b * ODIM + o] = cw;  // chosen_w = out 1
    }
}

// K2: sx-only argmin + chosen_x. Grid 1024 = (b, oh), 256 thr. Barrier-free
// per-wave relx streaming, DOUBLE-buffered; 17 KB LDS. Coalesced store.
#define OCH 8
#define ONC (IDIM / OCH)   // 32
__global__ __launch_bounds__(256) void outx_kernel(const float* __restrict__ x,
                                                   const float* __restrict__ w,
                                                   const float* __restrict__ relx,
                                                   float* __restrict__ out) {
    __shared__ float rbuf[4][2][OCH * 64];   // 16 KB (per-wave private)
    __shared__ float xrow[IDIM];             // 1 KB
    const int tid = threadIdx.x;             // 0..255
    const int b   = blockIdx.x >> 1;         // 0..511
    const int obase = (blockIdx.x & 1) * 256;
    const int l = tid & 63, wv = tid >> 6;   // 4 waves
    const int colbase = obase + wv * 64;
    const int o = obase + tid;

    xrow[tid] = x[(size_t)b * IDIM + tid];   // coalesced (256 == IDIM)
    asm volatile("s_waitcnt vmcnt(0)" ::: "memory");  // clean count
    #pragma unroll
    for (int rr = 0; rr < 2; ++rr) {         // issue chunk 0 (2 ops/wave)
        size_t row = (size_t)(rr * 4 + (l >> 4));
        async_cp16(relx + row * ODIM + colbase + (l & 15) * 4,
                   &rbuf[wv][0][rr * 256 + l * 4]);
    }
    asm volatile("s_waitcnt lgkmcnt(0)" ::: "memory");  // xrow write done
    __builtin_amdgcn_s_barrier();                       // xrow visible (only barrier)

    float bx = (float)INFINITY; int ix = 0;  // +INF seed == first-occurrence
    for (int c = 0; c < ONC; ++c) {
        if (c + 1 < ONC) {                   // issue c+1 into the other buffer
            #pragma unroll
            for (int rr = 0; rr < 2; ++rr) {
                size_t row = (size_t)((c + 1) * OCH + rr * 4 + (l >> 4));
                async_cp16(relx + row * ODIM + colbase + (l & 15) * 4,
                           &rbuf[wv][(c + 1) & 1][rr * 256 + l * 4]);
            }
            asm volatile("s_waitcnt vmcnt(2)" ::: "memory");  // c landed
        } else {
            asm volatile("s_waitcnt vmcnt(0)" ::: "memory");
        }
        const float* rb = &rbuf[wv][c & 1][0];
        #pragma unroll
        for (int u = 0; u < OCH; ++u) {
            int ii = c * OCH + u;
            float rl = rb[u * 64 + l];       // 2-way bank (free)
            float xv = xrow[ii];             // uniform broadcast
            float s  = __fsub_rn(__fadd_rn(xv, rl), __fmul_rn(xv, rl));
            if (np_argmin_better(s, bx)) { bx = s; ix = ii; }  // sequential
        }
        asm volatile("" ::: "memory");
    }
    float cx = fmaxf(xrow[ix], w[(size_t)ix * ODIM + o]);  // 1 gather/thread
    out[(size_t)b * ODIM + o] = cx;                        // chosen_x = out 0
}

extern "C" void kernel_launch(void* const* d_in, const int* in_sizes, int n_in,
                              void* d_out, int out_size, void* d_ws, size_t ws_size,
                              hipStream_t stream) {
    const float* x = (const float*)d_in[0];  // (B, I)
    const float* w = (const float*)d_in[1];  // (I, O)
    const float* t = (const float*)d_in[2];  // (B, O)
    float* out = (float*)d_out;              // [chosen_x | chosen_w]

    float* relx = (float*)d_ws;              // I*O*4 = 512 KB

    hipLaunchKernelGGL(rel_fused_kernel, dim3(256 + ODIM), dim3(512), 0, stream,
                       x, w, t, relx, out);
    hipLaunchKernelGGL(outx_kernel, dim3(2 * BDIM), dim3(256), 0, stream,
                       x, w, relx, out);
}

// Round 12
// 73.410 us; speedup vs baseline: 1.8225x; 1.2918x over previous
//
#include <hip/hip_runtime.h>
#include <math.h>

#define BDIM 512
#define IDIM 256
#define ODIM 512

// 16B table entry: correctly-rounded fp64 reciprocal of den, comp, raw value.
struct __align__(16) XT { double r; float c; float pad; };

// jnp.minimum(q, 1.0): NaN-propagating min with 1.0 (slow/general path)
__device__ __forceinline__ float np_min1(float q) {
    float m = fminf(q, 1.0f);
    return (q != q) ? q : m;
}

// np.argmin update: strict < (first occurrence wins), NaN-first & sticky.
__device__ __forceinline__ bool np_argmin_better(float s, float best) {
    return (s < best) || (isnan(s) && !isnan(best));
}

// Correctly-rounded fp32 divide num/den as RN32(num * r), r = RN64(1/den).
// (no fp32/fp32 quotient is a 25-bit midpoint -> exclusion >= 2^-49 >> 2^-51.9
// rel err; den==0 -> r=+INF -> IEEE num/0.) Bit-stable since R2 (absmax pinned).
__device__ __forceinline__ float q32(float num, double r) {
    return (float)((double)num * r);
}

// async global->LDS, 16B/lane; global src is PER-LANE, LDS dest = base+lane*16.
typedef const __attribute__((address_space(1))) unsigned int* gu32p;
typedef __attribute__((address_space(3))) unsigned int* lu32p;
__device__ __forceinline__ void async_cp16(const float* g, float* l) {
    __builtin_amdgcn_global_load_lds((gu32p)(const void*)g, (lu32p)(void*)l, 16, 0, 0);
}

// FUSED: role by bid%3 (interleaved for CU balance):
//   r==0 -> relx role, i = bid/3           (256 blocks)
//   r>0  -> relw+ind_w+chosen_w, o=2k+r-1  (512 blocks)
// 40 KB LDS union -> 4 blocks/CU. den==0 detected per block -> fast loops
// (bit-identical when no zeros); global flag for outx via device atomicOr.
#define XCH 8
#define XNC (BDIM / XCH)   // 64
__global__ __launch_bounds__(512) void rel_fused_kernel(const float* __restrict__ x,
                                                        const float* __restrict__ w,
                                                        const float* __restrict__ t,
                                                        float* __restrict__ relx,
                                                        float* __restrict__ out,
                                                        int* __restrict__ gflag) {
    __shared__ __align__(16) char lds[40960];
    const int tid = threadIdx.x;             // 0..511
    const int bid = blockIdx.x;
    const int role = bid % 3, k = bid / 3;

    if (role == 0) {
        // ---------------- relx role (i = k) ----------------
        float (*tbuf)[2][XCH * 64] = (float (*)[2][XCH * 64])lds;  // 8w x 2 x 2KB = 32 KB
        XT* xtab = (XT*)(lds + 32768);                             // 8 KB
        float* zflags = (float*)lds;         // reuse tbuf[0] pre-stream for 8 wave-flags
        const int i = k;                     // 0..255
        const int l = tid & 63, wv = tid >> 6;   // 8 waves
        const int colbase = wv * 64;         // wave's 64-col window

        bool myz;
        {   // build x-table: one strided gather + one fp64 divide per thread
            float xv  = x[(size_t)tid * IDIM + i];
            float xc  = __fsub_rn(1.0f, xv);     // x_comp
            float den = __fsub_rn(1.0f, xc);     // NOT simply xv (rounding!)
            XT e; e.r = 1.0 / (double)den; e.c = xc; e.pad = xv;
            xtab[tid] = e;                       // den==0 -> r=+INF (IEEE)
            myz = (den == 0.0f);
        }
        // cross-wave zero-flag exchange through tbuf[0] (before streaming)
        if (l == 0) zflags[wv] = __any(myz) ? 1.0f : 0.0f;
        __syncthreads();                     // xtab + zflags visible
        float zf = 0.0f;
        #pragma unroll
        for (int u = 0; u < 8; ++u) zf += zflags[u];
        const bool anyz = (zf != 0.0f);
        if (anyz && tid == 0) atomicOr(gflag, 1);   // device-scope, for outx
        __syncthreads();                     // all flag reads done before cp16 lands

        asm volatile("s_waitcnt vmcnt(0)" ::: "memory");  // clean count
        #pragma unroll
        for (int rr = 0; rr < 2; ++rr) {     // issue chunk 0 (2 ops/wave)
            size_t row = (size_t)(rr * 4 + (l >> 4));
            async_cp16(t + row * ODIM + colbase + (l & 15) * 4,
                       &tbuf[wv][0][rr * 256 + l * 4]);
        }

        float S = 0.0f, D = 0.0f;
        for (int c = 0; c < XNC; ++c) {
            if (c + 1 < XNC) {               // issue c+1 into the other buffer
                #pragma unroll
                for (int rr = 0; rr < 2; ++rr) {
                    size_t row = (size_t)((c + 1) * XCH + rr * 4 + (l >> 4));
                    async_cp16(t + row * ODIM + colbase + (l & 15) * 4,
                               &tbuf[wv][(c + 1) & 1][rr * 256 + l * 4]);
                }
                asm volatile("s_waitcnt vmcnt(2)" ::: "memory");  // c landed
            } else {
                asm volatile("s_waitcnt vmcnt(0)" ::: "memory");
            }
            const float* tb = &tbuf[wv][c & 1][0];
            if (!anyz) {                     // FAST: no zeros -> q finite, bit-identical
                #pragma unroll
                for (int u = 0; u < XCH; ++u) {
                    float tv = tb[u * 64 + l];
                    XT e = xtab[c * XCH + u];        // uniform broadcast b128
                    float tc  = __fsub_rn(1.0f, tv);
                    float num = __fsub_rn(tc, e.c);
                    float q   = fminf(q32(num, e.r), 1.0f);
                    S = __fadd_rn(S, q);             // exact sequential order
                    D = __fadd_rn(D, e.c);
                }
            } else {                         // SLOW: exact IEEE/NaN semantics
                #pragma unroll
                for (int u = 0; u < XCH; ++u) {
                    float tv = tb[u * 64 + l];
                    XT e = xtab[c * XCH + u];
                    float tc  = __fsub_rn(1.0f, tv);
                    float num = __fsub_rn(tc, e.c);
                    float q   = np_min1(q32(num, e.r));
                    S = __fadd_rn(S, q);
                    D = __fadd_rn(D, e.c);
                }
            }
            asm volatile("" ::: "memory");
        }
        relx[(size_t)i * ODIM + tid] = __fsub_rn(1.0f, __fdiv_rn(S, D));
    } else {
        // ---------------- relw + ind_w + chosen_w role ----------------
        XT*    wtab   = (XT*)lds;            // 4 KB
        float* wraw   = (float*)(lds + 4096);// 1 KB
        float* zflags = (float*)(lds + 5120);// 4 wave-flags
        const int b = tid;                   // 0..511
        const int o = 2 * k + (role - 1);    // 0..511
        bool myz = false;
        if (b < IDIM) {
            float wvv = w[(size_t)b * ODIM + o]; // strided gather, once
            float wc  = __fsub_rn(1.0f, wvv);    // w_comp
            float den = __fsub_rn(1.0f, wc);
            XT e; e.r = 1.0 / (double)den; e.c = wc; e.pad = wvv;
            wtab[b] = e;
            wraw[b] = wvv;
            myz = (den == 0.0f);
        }
        const int l = tid & 63, wv = tid >> 6;
        if (wv < 4 && l == 0) zflags[wv] = 0.0f;   // init (waves 4-7 have no builds)
        float tc = __fsub_rn(1.0f, t[(size_t)b * ODIM + o]);  // strided, once
        __syncthreads();
        if (wv < 4 && __any(myz) && l == 0) zflags[wv] = 1.0f;
        __syncthreads();
        float zf = zflags[0] + zflags[1] + zflags[2] + zflags[3];
        const bool anyz = (zf != 0.0f);

        float S = 0.0f, D = 0.0f;
        float best = (float)INFINITY; int iw = 0;   // +INF seed == first-occ
        if (!anyz) {                         // FAST paths (bit-identical, finite)
            #pragma unroll 8
            for (int i = 0; i < IDIM; ++i) {
                XT e = wtab[i];              // uniform broadcast b128
                float num = __fsub_rn(tc, e.c);
                float q   = fminf(q32(num, e.r), 1.0f);
                S = __fadd_rn(S, q);
                D = __fadd_rn(D, e.c);
            }
            float rw = __fsub_rn(1.0f, __fdiv_rn(S, D));
            #pragma unroll 16
            for (int i = 0; i < IDIM; ++i) {
                float wvv = wraw[i];         // uniform broadcast b32
                float s = __fsub_rn(__fadd_rn(wvv, rw), __fmul_rn(wvv, rw));
                bool lt = (s < best);        // strict < : first occurrence
                best = lt ? s : best; iw = lt ? i : iw;
            }
            float cw = fmaxf(x[(size_t)b * IDIM + iw], wraw[iw]);
            out[(size_t)BDIM * ODIM + (size_t)b * ODIM + o] = cw;
        } else {                             // SLOW: exact IEEE/NaN semantics
            #pragma unroll 8
            for (int i = 0; i < IDIM; ++i) {
                XT e = wtab[i];
                float num = __fsub_rn(tc, e.c);
                float q   = np_min1(q32(num, e.r));
                S = __fadd_rn(S, q);
                D = __fadd_rn(D, e.c);
            }
            float rw = __fsub_rn(1.0f, __fdiv_rn(S, D));
            #pragma unroll 8
            for (int i = 0; i < IDIM; ++i) {
                float wvv = wraw[i];
                float s = __fsub_rn(__fadd_rn(wvv, rw), __fmul_rn(wvv, rw));
                if (np_argmin_better(s, best)) { best = s; iw = i; }
            }
            float cw = fmaxf(x[(size_t)b * IDIM + iw], wraw[iw]);
            out[(size_t)BDIM * ODIM + (size_t)b * ODIM + o] = cw;
        }
    }
}

// K2: sx-only argmin + chosen_x. Grid 1024 = (b, oh), 256 thr. Barrier-free
// per-wave relx streaming, double-buffered; fast/slow via gflag.
#define OCH 8
#define ONC (IDIM / OCH)   // 32
__global__ __launch_bounds__(256) void outx_kernel(const float* __restrict__ x,
                                                   const float* __restrict__ w,
                                                   const float* __restrict__ relx,
                                                   const int* __restrict__ gflag,
                                                   float* __restrict__ out) {
    __shared__ float rbuf[4][2][OCH * 64];   // 16 KB (per-wave private)
    __shared__ float xrow[IDIM];             // 1 KB
    const int tid = threadIdx.x;             // 0..255
    const int b   = blockIdx.x >> 1;         // 0..511
    const int obase = (blockIdx.x & 1) * 256;
    const int l = tid & 63, wv = tid >> 6;   // 4 waves
    const int colbase = obase + wv * 64;
    const int o = obase + tid;

    xrow[tid] = x[(size_t)b * IDIM + tid];   // coalesced (256 == IDIM)
    const bool anyz = (*gflag != 0);         // x had a zero -> relx may be INF/NaN
    asm volatile("s_waitcnt vmcnt(0)" ::: "memory");  // clean count
    #pragma unroll
    for (int rr = 0; rr < 2; ++rr) {         // issue chunk 0 (2 ops/wave)
        size_t row = (size_t)(rr * 4 + (l >> 4));
        async_cp16(relx + row * ODIM + colbase + (l & 15) * 4,
                   &rbuf[wv][0][rr * 256 + l * 4]);
    }
    asm volatile("s_waitcnt lgkmcnt(0)" ::: "memory");  // xrow write done
    __builtin_amdgcn_s_barrier();                       // xrow visible (only barrier)

    float bx = (float)INFINITY; int ix = 0;  // +INF seed == first-occurrence
    for (int c = 0; c < ONC; ++c) {
        if (c + 1 < ONC) {                   // issue c+1 into the other buffer
            #pragma unroll
            for (int rr = 0; rr < 2; ++rr) {
                size_t row = (size_t)((c + 1) * OCH + rr * 4 + (l >> 4));
                async_cp16(relx + row * ODIM + colbase + (l & 15) * 4,
                           &rbuf[wv][(c + 1) & 1][rr * 256 + l * 4]);
            }
            asm volatile("s_waitcnt vmcnt(2)" ::: "memory");  // c landed
        } else {
            asm volatile("s_waitcnt vmcnt(0)" ::: "memory");
        }
        const float* rb = &rbuf[wv][c & 1][0];
        if (!anyz) {                         // FAST: all scores finite
            #pragma unroll
            for (int u = 0; u < OCH; ++u) {
                int ii = c * OCH + u;
                float rl = rb[u * 64 + l];
                float xv = xrow[ii];
                float s  = __fsub_rn(__fadd_rn(xv, rl), __fmul_rn(xv, rl));
                bool lt = (s < bx);          // strict < : first occurrence
                bx = lt ? s : bx; ix = lt ? ii : ix;
            }
        } else {                             // SLOW: exact NaN-first semantics
            #pragma unroll
            for (int u = 0; u < OCH; ++u) {
                int ii = c * OCH + u;
                float rl = rb[u * 64 + l];
                float xv = xrow[ii];
                float s  = __fsub_rn(__fadd_rn(xv, rl), __fmul_rn(xv, rl));
                if (np_argmin_better(s, bx)) { bx = s; ix = ii; }
            }
        }
        asm volatile("" ::: "memory");
    }
    float cx = fmaxf(xrow[ix], w[(size_t)ix * ODIM + o]);  // 1 gather/thread
    out[(size_t)b * ODIM + o] = cx;                        // chosen_x = out 0
}

extern "C" void kernel_launch(void* const* d_in, const int* in_sizes, int n_in,
                              void* d_out, int out_size, void* d_ws, size_t ws_size,
                              hipStream_t stream) {
    const float* x = (const float*)d_in[0];  // (B, I)
    const float* w = (const float*)d_in[1];  // (I, O)
    const float* t = (const float*)d_in[2];  // (B, O)
    float* out = (float*)d_out;              // [chosen_x | chosen_w]

    float* relx = (float*)d_ws;              // I*O*4 = 512 KB
    int* gflag  = (int*)((char*)d_ws + (size_t)IDIM * ODIM * 4);

    hipMemsetAsync(gflag, 0, 4, stream);
    hipLaunchKernelGGL(rel_fused_kernel, dim3(768), dim3(512), 0, stream,
                       x, w, t, relx, out, gflag);
    hipLaunchKernelGGL(outx_kernel, dim3(2 * BDIM), dim3(256), 0, stream,
                       x, w, relx, gflag, out);
}